// Round 14
// baseline (65.792 us; speedup 1.0000x reference)
//
#include <hip/hip_runtime.h>
#include <math.h>

#define Lc 128
#define Rc 1024
#define Pc 8
#define Ec 64
#define Fc 64

// exp(-((d-mu)/sigma)^2) = exp2(-(C*(d-mu))^2), C = (1/0.15625)*sqrt(log2(e))
#define CSCALE   7.68718341623328f
#define MU_STEP  0.15873015873015873f   // 10/63
#define MUC      (MU_STEP * CSCALE)

#define NBLKM 1024   // ff_mfma blocks: 16 ng x 8 mt x 8 ez  (4 blocks/CU)

typedef __attribute__((ext_vector_type(8))) short short8;   // 8 bf16 (4 VGPRs)
typedef __attribute__((ext_vector_type(4))) float f32x4;

__device__ __forceinline__ unsigned short bf16_rn(float x) {
    unsigned int u = __float_as_uint(x);
    u += 0x7FFF + ((u >> 16) & 1);
    return (unsigned short)(u >> 16);
}
__device__ __forceinline__ float bf16_f32(unsigned short b) {
    return __uint_as_float(((unsigned int)b) << 16);
}

#define N4_LIG (Lc * Ec * Fc / 4)   // 131072
#define N4_REC (Rc * Ec * Fc / 4)   // 1048576

// ---- split-convert BOTH tensors f32 -> (hi,lo) bf16, [g=row*64+e][hi 0..63 | lo 64..127]
__global__ __launch_bounds__(256)
void ff_cvt(const float* __restrict__ lig_feat, const float* __restrict__ rec_feat,
            unsigned short* __restrict__ ligP, unsigned short* __restrict__ recP)
{
    int i = blockIdx.x * 256 + threadIdx.x;
    const float* src;
    unsigned short* dst;
    int idx;
    if (i < N4_LIG) { src = lig_feat; dst = ligP; idx = i; }
    else            { src = rec_feat; dst = recP; idx = i - N4_LIG; }
    float4 v = ((const float4*)src)[idx];
    int s0 = idx * 4;
    size_t g = (size_t)(s0 >> 6);
    int kb = s0 & 63;
    ushort4 h, l;
    h.x = bf16_rn(v.x); l.x = bf16_rn(v.x - bf16_f32(h.x));
    h.y = bf16_rn(v.y); l.y = bf16_rn(v.y - bf16_f32(h.y));
    h.z = bf16_rn(v.z); l.z = bf16_rn(v.z - bf16_f32(h.z));
    h.w = bf16_rn(v.w); l.w = bf16_rn(v.w - bf16_f32(h.w));
    *(ushort4*)(dst + g * 128 + kb)      = h;
    *(ushort4*)(dst + g * 128 + 64 + kb) = l;
}

// ---- fused: per (16l x 16r) C-tile, per e: 6 split-MFMAs -> fold exp2 into us[p] ----
// dsc lives in a wave-private LDS table (NOT registers): loop-persistent register
// demand drops to ~58 < the allocator's observed 64-reg ceiling -> no spill.
__global__ __launch_bounds__(256, 4)
void ff_mfma(const unsigned short* __restrict__ ligP,
             const unsigned short* __restrict__ recP,
             const float* __restrict__ lig_coords,
             const float* __restrict__ rec_coords,
             float* __restrict__ partial)
{
    __shared__ float dscs[4][Pc][4][64];   // 32 KB; reused as reduce scratch at the end

    const int tid  = threadIdx.x;
    const int lane = tid & 63;
    const int w    = tid >> 6;
    const int n16  = lane & 15;
    const int kg   = lane >> 4;

    // bid&7 = XCD: each XCD owns 2 n-groups (128 rec rows, 2 MB recP slice, L2-resident)
    const int bid = blockIdx.x;
    const int loc = bid >> 3;
    const int ng  = (bid & 7) * 2 + (loc & 1);
    const int mt  = (loc >> 1) & 7;
    const int ez  = loc >> 4;              // 0..7
    const int nt  = ng * 4 + w;
    const int r   = nt * 16 + n16;
    const int e0  = ez * 8;

    // distances -> LDS (wave-private slice; same-wave readback needs no barrier)
    {
        const float rcx = rec_coords[r * 3 + 0];
        const float rcy = rec_coords[r * 3 + 1];
        const float rcz = rec_coords[r * 3 + 2];
        #pragma unroll
        for (int reg = 0; reg < 4; ++reg) {
            const int l = mt * 16 + kg * 4 + reg;
            #pragma unroll
            for (int p = 0; p < Pc; ++p) {
                const float* lcp = lig_coords + ((size_t)p * Lc + l) * 3;
                float dx = lcp[0] - rcx;
                float dy = lcp[1] - rcy;
                float dz = lcp[2] - rcz;
                dscs[w][p][reg][lane] = sqrtf(dx * dx + dy * dy + dz * dz) * CSCALE;
            }
        }
    }

    const unsigned short* ap = ligP + ((size_t)(mt * 16 + n16) * Ec + e0) * 128 + kg * 8;
    const unsigned short* bp = recP + ((size_t)r * Ec + e0) * 128 + kg * 8;
    const float* dbase = &dscs[w][0][0][lane];

    float us[Pc];
    #pragma unroll
    for (int p = 0; p < Pc; ++p) us[p] = 0.f;

    for (int te = 0; te < 8; ++te) {
        const unsigned short* a = ap + (size_t)te * 128;
        const unsigned short* b = bp + (size_t)te * 128;
        short8 Ah0 = *(const short8*)(a);
        short8 Ah1 = *(const short8*)(a + 32);
        short8 Al0 = *(const short8*)(a + 64);
        short8 Al1 = *(const short8*)(a + 96);
        short8 Bh0 = *(const short8*)(b);
        short8 Bh1 = *(const short8*)(b + 32);
        short8 Bl0 = *(const short8*)(b + 64);
        short8 Bl1 = *(const short8*)(b + 96);

        // atn tile for this e: hh + lh + hl (drop ll, ~2^-18 rel)
        f32x4 acc = {0.f, 0.f, 0.f, 0.f};
        acc = __builtin_amdgcn_mfma_f32_16x16x32_bf16(Ah0, Bh0, acc, 0, 0, 0);
        acc = __builtin_amdgcn_mfma_f32_16x16x32_bf16(Ah1, Bh1, acc, 0, 0, 0);
        acc = __builtin_amdgcn_mfma_f32_16x16x32_bf16(Al0, Bh0, acc, 0, 0, 0);
        acc = __builtin_amdgcn_mfma_f32_16x16x32_bf16(Al1, Bh1, acc, 0, 0, 0);
        acc = __builtin_amdgcn_mfma_f32_16x16x32_bf16(Ah0, Bl0, acc, 0, 0, 0);
        acc = __builtin_amdgcn_mfma_f32_16x16x32_bf16(Ah1, Bl1, acc, 0, 0, 0);

        // fold into pose accumulators; dsc re-read from LDS each step.
        // Launder the pointer so LICM can't hoist the 32 reads into registers.
        const float* dq = dbase;
        asm("" : "+v"(dq));
        const float musC = (float)(e0 + te) * MUC;
        #pragma unroll
        for (int reg = 0; reg < 4; ++reg) {
            const float av = acc[reg];
            #pragma unroll
            for (int p = 0; p < Pc; ++p) {
                const float t = dq[(p * 4 + reg) * 64] - musC;   // ds_read_b32, conflict-free
                us[p] = fmaf(av, __builtin_amdgcn_exp2f(-t * t), us[p]);
            }
        }
    }

    // butterfly over 64 lanes, then across the 4 waves (reuse dscs as scratch)
    #pragma unroll
    for (int p = 0; p < Pc; ++p) {
        float v = us[p];
        #pragma unroll
        for (int off = 32; off >= 1; off >>= 1)
            v += __shfl_xor(v, off, 64);
        us[p] = v;
    }
    __syncthreads();   // everyone done reading dscs
    if (lane == 0) {
        #pragma unroll
        for (int p = 0; p < Pc; ++p) dscs[0][0][0][w * Pc + p] = us[p];
    }
    __syncthreads();
    if (tid < Pc) {
        float s = 0.f;
        #pragma unroll
        for (int k = 0; k < 4; ++k) s += dscs[0][0][0][k * Pc + tid];
        partial[(size_t)bid * Pc + tid] = s;
    }
}

// reduce NBLKM block-partials x 8 poses -> 8 outputs
__global__ void ff_reduce(const float* __restrict__ partial, float* __restrict__ out)
{
    const int w    = threadIdx.x >> 6;
    const int lane = threadIdx.x & 63;
    float v = 0.f;
    #pragma unroll
    for (int j = 0; j < NBLKM / 64; ++j)
        v += partial[(size_t)(lane + 64 * j) * Pc + w];
    #pragma unroll
    for (int off = 32; off >= 1; off >>= 1)
        v += __shfl_xor(v, off, 64);
    if (lane == 0) out[w] = 0.1f * v;
}

extern "C" void kernel_launch(void* const* d_in, const int* in_sizes, int n_in,
                              void* d_out, int out_size, void* d_ws, size_t ws_size,
                              hipStream_t stream)
{
    const float* lig_feat   = (const float*)d_in[0];
    const float* rec_feat   = (const float*)d_in[1];
    const float* lig_coords = (const float*)d_in[2];
    const float* rec_coords = (const float*)d_in[3];
    float* out = (float*)d_out;

    float*          partial = (float*)d_ws;                                   // 32 KB
    unsigned short* ligP    = (unsigned short*)((char*)d_ws + 65536);         // 2 MB
    unsigned short* recP    = (unsigned short*)((char*)d_ws + 65536 + (2u << 20)); // 16 MB

    ff_cvt<<<(N4_LIG + N4_REC) / 256, 256, 0, stream>>>(lig_feat, rec_feat, ligP, recP);
    ff_mfma<<<NBLKM, 256, 0, stream>>>(ligP, recP, lig_coords, rec_coords, partial);
    ff_reduce<<<1, 512, 0, stream>>>(partial, out);
}

// Round 15
// 61.214 us; speedup vs baseline: 1.0748x; 1.0748x over previous
//
#include <hip/hip_runtime.h>
#include <math.h>

#define Lc 128
#define Rc 1024
#define Pc 8
#define Ec 64
#define Fc 64

// exp(-((d-mu)/sigma)^2) = exp2(-(C*(d-mu))^2), C = (1/0.15625)*sqrt(log2(e))
#define CSCALE   7.68718341623328f
#define MU_STEP  0.15873015873015873f   // 10/63
#define MUC      (MU_STEP * CSCALE)

#define NBLKM 1024   // ff_mfma blocks: 16 ng x 8 mt x 8 ez  (4 blocks/CU)

typedef __attribute__((ext_vector_type(8))) short short8;   // 8 bf16 (4 VGPRs)
typedef __attribute__((ext_vector_type(4))) float f32x4;

__device__ __forceinline__ unsigned short bf16_rn(float x) {
    unsigned int u = __float_as_uint(x);
    u += 0x7FFF + ((u >> 16) & 1);
    return (unsigned short)(u >> 16);
}
__device__ __forceinline__ float bf16_f32(unsigned short b) {
    return __uint_as_float(((unsigned int)b) << 16);
}

#define N4_LIG (Lc * Ec * Fc / 4)   // 131072
#define N4_REC (Rc * Ec * Fc / 4)   // 1048576

// ---- split-convert BOTH tensors f32 -> (hi,lo) bf16, [g=row*64+e][hi 0..63 | lo 64..127]
__global__ __launch_bounds__(256)
void ff_cvt(const float* __restrict__ lig_feat, const float* __restrict__ rec_feat,
            unsigned short* __restrict__ ligP, unsigned short* __restrict__ recP)
{
    int i = blockIdx.x * 256 + threadIdx.x;
    const float* src;
    unsigned short* dst;
    int idx;
    if (i < N4_LIG) { src = lig_feat; dst = ligP; idx = i; }
    else            { src = rec_feat; dst = recP; idx = i - N4_LIG; }
    float4 v = ((const float4*)src)[idx];
    int s0 = idx * 4;
    size_t g = (size_t)(s0 >> 6);
    int kb = s0 & 63;
    ushort4 h, l;
    h.x = bf16_rn(v.x); l.x = bf16_rn(v.x - bf16_f32(h.x));
    h.y = bf16_rn(v.y); l.y = bf16_rn(v.y - bf16_f32(h.y));
    h.z = bf16_rn(v.z); l.z = bf16_rn(v.z - bf16_f32(h.z));
    h.w = bf16_rn(v.w); l.w = bf16_rn(v.w - bf16_f32(h.w));
    *(ushort4*)(dst + g * 128 + kb)      = h;
    *(ushort4*)(dst + g * 128 + 64 + kb) = l;
}

// ---- fused: per (16l x 16r) C-tile: split-MFMAs for 2 e's -> fold exp2 into us[p] ----
// dsc lives in a wave-private XOR-swizzled f32x4 LDS table. Reads are REAL ds_read_b128
// (shared array indexed directly -> addrspace(3) visible); an opaque integer offset
// (asm volatile, fresh each iteration) defeats LICM without hiding the address space
// (the round-14 pointer-launder compiled to flat_load -> 45 us).
__global__ __launch_bounds__(256, 4)
void ff_mfma(const unsigned short* __restrict__ ligP,
             const unsigned short* __restrict__ recP,
             const float* __restrict__ lig_coords,
             const float* __restrict__ rec_coords,
             float* __restrict__ partial)
{
    __shared__ f32x4 dsc4[4][64][8];   // 32 KB; reused as reduce scratch at the end

    const int tid  = threadIdx.x;
    const int lane = tid & 63;
    const int w    = tid >> 6;
    const int n16  = lane & 15;
    const int kg   = lane >> 4;
    const int m7   = lane & 7;

    // bid&7 = XCD: each XCD owns 2 n-groups (128 rec rows, 2 MB recP slice, L2-resident)
    const int bid = blockIdx.x;
    const int loc = bid >> 3;
    const int ng  = (bid & 7) * 2 + (loc & 1);
    const int mt  = (loc >> 1) & 7;
    const int ez  = loc >> 4;              // 0..7
    const int nt  = ng * 4 + w;
    const int r   = nt * 16 + n16;
    const int e0  = ez * 8;

    // distances -> wave-private LDS table (f32x4 over reg; XOR slot swizzle)
    {
        const float rcx = rec_coords[r * 3 + 0];
        const float rcy = rec_coords[r * 3 + 1];
        const float rcz = rec_coords[r * 3 + 2];
        #pragma unroll
        for (int p = 0; p < Pc; ++p) {
            f32x4 v;
            #pragma unroll
            for (int reg = 0; reg < 4; ++reg) {
                const int l = mt * 16 + kg * 4 + reg;
                const float* lcp = lig_coords + ((size_t)p * Lc + l) * 3;
                float dx = lcp[0] - rcx;
                float dy = lcp[1] - rcy;
                float dz = lcp[2] - rcz;
                v[reg] = sqrtf(dx * dx + dy * dy + dz * dz) * CSCALE;
            }
            dsc4[w][lane][p ^ m7] = v;
        }
    }

    const unsigned short* ap = ligP + ((size_t)(mt * 16 + n16) * Ec + e0) * 128 + kg * 8;
    const unsigned short* bp = recP + ((size_t)r * Ec + e0) * 128 + kg * 8;

    float us[Pc];
    #pragma unroll
    for (int p = 0; p < Pc; ++p) us[p] = 0.f;

    #pragma unroll
    for (int tp = 0; tp < 4; ++tp) {       // 4 pairs = 8 e's
        const int e = e0 + 2 * tp;

        // ---- e (even): hh + lh + hl (drop ll, ~2^-18 rel) ----
        f32x4 accA = {0.f, 0.f, 0.f, 0.f};
        {
            const unsigned short* a = ap + (size_t)(2 * tp) * 128;
            const unsigned short* b = bp + (size_t)(2 * tp) * 128;
            short8 Ah0 = *(const short8*)(a);
            short8 Ah1 = *(const short8*)(a + 32);
            short8 Al0 = *(const short8*)(a + 64);
            short8 Al1 = *(const short8*)(a + 96);
            short8 Bh0 = *(const short8*)(b);
            short8 Bh1 = *(const short8*)(b + 32);
            short8 Bl0 = *(const short8*)(b + 64);
            short8 Bl1 = *(const short8*)(b + 96);
            accA = __builtin_amdgcn_mfma_f32_16x16x32_bf16(Ah0, Bh0, accA, 0, 0, 0);
            accA = __builtin_amdgcn_mfma_f32_16x16x32_bf16(Ah1, Bh1, accA, 0, 0, 0);
            accA = __builtin_amdgcn_mfma_f32_16x16x32_bf16(Al0, Bh0, accA, 0, 0, 0);
            accA = __builtin_amdgcn_mfma_f32_16x16x32_bf16(Al1, Bh1, accA, 0, 0, 0);
            accA = __builtin_amdgcn_mfma_f32_16x16x32_bf16(Ah0, Bl0, accA, 0, 0, 0);
            accA = __builtin_amdgcn_mfma_f32_16x16x32_bf16(Ah1, Bl1, accA, 0, 0, 0);
        }
        // ---- e+1 (odd): fragments reloaded (regs reused; frag state stays 32) ----
        f32x4 accB = {0.f, 0.f, 0.f, 0.f};
        {
            const unsigned short* a = ap + (size_t)(2 * tp + 1) * 128;
            const unsigned short* b = bp + (size_t)(2 * tp + 1) * 128;
            short8 Ah0 = *(const short8*)(a);
            short8 Ah1 = *(const short8*)(a + 32);
            short8 Al0 = *(const short8*)(a + 64);
            short8 Al1 = *(const short8*)(a + 96);
            short8 Bh0 = *(const short8*)(b);
            short8 Bh1 = *(const short8*)(b + 32);
            short8 Bl0 = *(const short8*)(b + 64);
            short8 Bl1 = *(const short8*)(b + 96);
            accB = __builtin_amdgcn_mfma_f32_16x16x32_bf16(Ah0, Bh0, accB, 0, 0, 0);
            accB = __builtin_amdgcn_mfma_f32_16x16x32_bf16(Ah1, Bh1, accB, 0, 0, 0);
            accB = __builtin_amdgcn_mfma_f32_16x16x32_bf16(Al0, Bh0, accB, 0, 0, 0);
            accB = __builtin_amdgcn_mfma_f32_16x16x32_bf16(Al1, Bh1, accB, 0, 0, 0);
            accB = __builtin_amdgcn_mfma_f32_16x16x32_bf16(Ah0, Bl0, accB, 0, 0, 0);
            accB = __builtin_amdgcn_mfma_f32_16x16x32_bf16(Ah1, Bl1, accB, 0, 0, 0);
        }

        // ---- fold both e's; dsc via ds_read_b128, opaque offset defeats LICM ----
        int lofs = 0;
        asm volatile("" : "+v"(lofs));     // fresh opaque 0 every iteration
        const float musC = (float)e * MUC;
        #pragma unroll
        for (int p = 0; p < Pc; ++p) {
            const f32x4 dv = dsc4[w][lane][(p ^ m7) + lofs];
            #pragma unroll
            for (int reg = 0; reg < 4; ++reg) {
                const float tA = dv[reg] - musC;
                const float tB = tA - MUC;
                us[p] = fmaf(accA[reg], __builtin_amdgcn_exp2f(-tA * tA), us[p]);
                us[p] = fmaf(accB[reg], __builtin_amdgcn_exp2f(-tB * tB), us[p]);
            }
        }
    }

    // butterfly over 64 lanes, then across the 4 waves (reuse dsc4 as scratch)
    #pragma unroll
    for (int p = 0; p < Pc; ++p) {
        float v = us[p];
        #pragma unroll
        for (int off = 32; off >= 1; off >>= 1)
            v += __shfl_xor(v, off, 64);
        us[p] = v;
    }
    __syncthreads();   // everyone done reading dsc4
    float* red = (float*)&dsc4[0][0][0];
    if (lane == 0) {
        #pragma unroll
        for (int p = 0; p < Pc; ++p) red[w * Pc + p] = us[p];
    }
    __syncthreads();
    if (tid < Pc) {
        float s = 0.f;
        #pragma unroll
        for (int k = 0; k < 4; ++k) s += red[k * Pc + tid];
        partial[(size_t)bid * Pc + tid] = s;
    }
}

// reduce NBLKM block-partials x 8 poses -> 8 outputs
__global__ void ff_reduce(const float* __restrict__ partial, float* __restrict__ out)
{
    const int w    = threadIdx.x >> 6;
    const int lane = threadIdx.x & 63;
    float v = 0.f;
    #pragma unroll
    for (int j = 0; j < NBLKM / 64; ++j)
        v += partial[(size_t)(lane + 64 * j) * Pc + w];
    #pragma unroll
    for (int off = 32; off >= 1; off >>= 1)
        v += __shfl_xor(v, off, 64);
    if (lane == 0) out[w] = 0.1f * v;
}

extern "C" void kernel_launch(void* const* d_in, const int* in_sizes, int n_in,
                              void* d_out, int out_size, void* d_ws, size_t ws_size,
                              hipStream_t stream)
{
    const float* lig_feat   = (const float*)d_in[0];
    const float* rec_feat   = (const float*)d_in[1];
    const float* lig_coords = (const float*)d_in[2];
    const float* rec_coords = (const float*)d_in[3];
    float* out = (float*)d_out;

    float*          partial = (float*)d_ws;                                   // 32 KB
    unsigned short* ligP    = (unsigned short*)((char*)d_ws + 65536);         // 2 MB
    unsigned short* recP    = (unsigned short*)((char*)d_ws + 65536 + (2u << 20)); // 16 MB

    ff_cvt<<<(N4_LIG + N4_REC) / 256, 256, 0, stream>>>(lig_feat, rec_feat, ligP, recP);
    ff_mfma<<<NBLKM, 256, 0, stream>>>(ligP, recP, lig_coords, rec_coords, partial);
    ff_reduce<<<1, 512, 0, stream>>>(partial, out);
}

// Round 16
// 46.478 us; speedup vs baseline: 1.4156x; 1.3171x over previous
//
#include <hip/hip_runtime.h>
#include <math.h>

#define Lc 128
#define Rc 1024
#define Pc 8
#define Ec 64
#define Fc 64

// exp(-((d-mu)/sigma)^2) = exp2(-(C*(d-mu))^2), C = (1/0.15625)*sqrt(log2(e))
#define CSCALE   7.68718341623328f
#define MU_STEP  0.15873015873015873f   // 10/63
#define MUC      (MU_STEP * CSCALE)

#define BM 32        // l per block
#define BN 32        // r per block
#define EC 8         // e per block
#define NBLKM ((Lc/BM)*(Rc/BN)*(Ec/EC))   // 4*32*8 = 1024

typedef __attribute__((ext_vector_type(8))) short short8;   // 8 bf16
typedef __attribute__((ext_vector_type(4))) float f32x4;

__device__ __forceinline__ unsigned short bf16_rn(float x) {
    unsigned int u = __float_as_uint(x);
    u += 0x7FFF + ((u >> 16) & 1);
    return (unsigned short)(u >> 16);
}
__device__ __forceinline__ float bf16_f32(unsigned short b) {
    return __uint_as_float(((unsigned int)b) << 16);
}

#define N4_LIG (Lc * Ec * Fc / 4)   // 131072
#define N4_REC (Rc * Ec * Fc / 4)   // 1048576

// ---- split-convert, NEW [e][row][hi 64 | lo 64] layout: per-e slices contiguous ----
__global__ __launch_bounds__(256)
void ff_cvt(const float* __restrict__ lig_feat, const float* __restrict__ rec_feat,
            unsigned short* __restrict__ ligE, unsigned short* __restrict__ recE)
{
    int i = blockIdx.x * 256 + threadIdx.x;
    const float* src;
    unsigned short* dst;
    int idx, nr;
    if (i < N4_LIG) { src = lig_feat; dst = ligE; idx = i; nr = Lc; }
    else            { src = rec_feat; dst = recE; idx = i - N4_LIG; nr = Rc; }
    float4 v = ((const float4*)src)[idx];
    int s0  = idx * 4;
    int g   = s0 >> 6;     // row*64 + e  (source is [row][e][f])
    int row = g >> 6;      // Ec == 64
    int e   = g & 63;
    int kb  = s0 & 63;
    size_t o = ((size_t)e * nr + row) * 128 + kb;
    ushort4 h, l;
    h.x = bf16_rn(v.x); l.x = bf16_rn(v.x - bf16_f32(h.x));
    h.y = bf16_rn(v.y); l.y = bf16_rn(v.y - bf16_f32(h.y));
    h.z = bf16_rn(v.z); l.z = bf16_rn(v.z - bf16_f32(h.z));
    h.w = bf16_rn(v.w); l.w = bf16_rn(v.w - bf16_f32(h.w));
    *(ushort4*)(dst + o)      = h;
    *(ushort4*)(dst + o + 64) = l;
}

// ---- fused GEMM+fold: cooperative LDS staging, per-wave 16x16 subtile ----
// Staging layout: stg[buf][A/B][row 0..31][slot 0..15][8 shorts]; 16B slot s of row
// stored at s ^ (row&15) (XOR swizzle -> conflict-light b128 reads).
__global__ __launch_bounds__(256, 2)
void ff_mfma(const unsigned short* __restrict__ ligE,
             const unsigned short* __restrict__ recE,
             const float* __restrict__ lig_coords,
             const float* __restrict__ rec_coords,
             float* __restrict__ partial)
{
    __shared__ unsigned short stg[2][2][32][16][8];   // 32 KB
    __shared__ float lcs[Pc][96];                     // lig coords slice (3 KB)
    __shared__ float rcs[96];                         // rec coords slice
    __shared__ float wred[4][Pc];

    const int tid  = threadIdx.x;
    const int lane = tid & 63;
    const int w    = tid >> 6;          // wave 0..3
    const int n16  = lane & 15;
    const int kg   = lane >> 4;         // 0..3
    const int sr   = w >> 1;            // subtile row (l)
    const int sc   = w & 1;             // subtile col (r)

    // grid decode; bid&7 = XCD (round-robin): each XCD owns 4 r-tiles (recE slice 2MB, L2-fit)
    const int bid = blockIdx.x;
    const int loc = bid >> 3;                   // 0..127
    const int rt  = (bid & 7) * 4 + (loc & 3);  // 0..31
    const int lt  = (loc >> 2) & 3;             // 0..3
    const int ez  = loc >> 4;                   // 0..7
    const int r0  = rt * BN;
    const int l0  = lt * BM;
    const int e0  = ez * EC;

    // coords -> LDS (cooperative, coalesced-ish)
    for (int i = tid; i < Pc * 96; i += 256) {
        int p = i / 96, q = i - p * 96;
        lcs[p][q] = lig_coords[p * (Lc * 3) + l0 * 3 + q];
    }
    if (tid < 96) rcs[tid] = rec_coords[r0 * 3 + tid];
    __syncthreads();

    // per-lane distances: l = sr*16 + kg*4 + reg, r = sc*16 + n16  (32 regs)
    float dsc[Pc][4];
    {
        const int rb = (sc * 16 + n16) * 3;
        const float rx = rcs[rb], ry = rcs[rb + 1], rz = rcs[rb + 2];
        #pragma unroll
        for (int reg = 0; reg < 4; ++reg) {
            const int lb = (sr * 16 + kg * 4 + reg) * 3;
            #pragma unroll
            for (int p = 0; p < Pc; ++p) {
                float dx = lcs[p][lb]     - rx;
                float dy = lcs[p][lb + 1] - ry;
                float dz = lcs[p][lb + 2] - rz;
                dsc[p][reg] = sqrtf(dx * dx + dy * dy + dz * dz) * CSCALE;
            }
        }
    }

    // staging roles: half = A/B, srow = row, sq = slot-quad (64 B per thread)
    const int half = tid >> 7;
    const int srow = (tid >> 2) & 31;
    const int sq   = tid & 3;
    const unsigned short* sbase = (half ? recE + ((size_t)r0 + srow) * 128
                                        : ligE + ((size_t)l0 + srow) * 128) + sq * 32;
    const size_t estr = (size_t)(half ? Rc : Lc) * 128;

    short8 pf[4];
    // prologue: stage e0 into buf 0
    #pragma unroll
    for (int j = 0; j < 4; ++j)
        pf[j] = *(const short8*)(sbase + (size_t)e0 * estr + j * 8);
    #pragma unroll
    for (int j = 0; j < 4; ++j)
        *(short8*)&stg[0][half][srow][(sq * 4 + j) ^ (srow & 15)][0] = pf[j];

    float us[Pc];
    #pragma unroll
    for (int p = 0; p < Pc; ++p) us[p] = 0.f;

    const int Arow = sr * 16 + n16;
    const int Brow = sc * 16 + n16;
#define RD(hf, rowv, slot) (*(const short8*)&stg[cur][hf][rowv][(slot) ^ ((rowv) & 15)][0])

    for (int t = 0; t < EC; ++t) {
        __syncthreads();                 // buf[t&1] visible to all waves
        const int cur = t & 1;

        // issue next e-slice loads early (latency hides under compute)
        if (t + 1 < EC) {
            #pragma unroll
            for (int j = 0; j < 4; ++j)
                pf[j] = *(const short8*)(sbase + (size_t)(e0 + t + 1) * estr + j * 8);
        }

        // 6 split-MFMAs, sequenced so only 3-4 fragments are live (hh + lh + hl)
        f32x4 acc = {0.f, 0.f, 0.f, 0.f};
        {
            short8 a0 = RD(0, Arow, kg);            // Ah0 (hi k 0..31)
            short8 b0 = RD(1, Brow, kg);            // Bh0
            acc = __builtin_amdgcn_mfma_f32_16x16x32_bf16(a0, b0, acc, 0, 0, 0);
            short8 a1 = RD(0, Arow, 8 + kg);        // Al0 (lo k 0..31)
            acc = __builtin_amdgcn_mfma_f32_16x16x32_bf16(a1, b0, acc, 0, 0, 0);
            short8 b1 = RD(1, Brow, 8 + kg);        // Bl0
            acc = __builtin_amdgcn_mfma_f32_16x16x32_bf16(a0, b1, acc, 0, 0, 0);
            a0 = RD(0, Arow, 4 + kg);               // Ah1 (hi k 32..63)
            b0 = RD(1, Brow, 4 + kg);               // Bh1
            acc = __builtin_amdgcn_mfma_f32_16x16x32_bf16(a0, b0, acc, 0, 0, 0);
            a1 = RD(0, Arow, 12 + kg);              // Al1
            acc = __builtin_amdgcn_mfma_f32_16x16x32_bf16(a1, b0, acc, 0, 0, 0);
            b1 = RD(1, Brow, 12 + kg);              // Bl1
            acc = __builtin_amdgcn_mfma_f32_16x16x32_bf16(a0, b1, acc, 0, 0, 0);
        }

        // fold atn into pose accumulators
        const float musC = (float)(e0 + t) * MUC;
        #pragma unroll
        for (int reg = 0; reg < 4; ++reg) {
            const float av = acc[reg];
            #pragma unroll
            for (int p = 0; p < Pc; ++p) {
                const float tt = dsc[p][reg] - musC;
                us[p] = fmaf(av, __builtin_amdgcn_exp2f(-tt * tt), us[p]);
            }
        }

        // write next e-slice into the other buffer (readers of it synced above)
        if (t + 1 < EC) {
            #pragma unroll
            for (int j = 0; j < 4; ++j)
                *(short8*)&stg[(t + 1) & 1][half][srow][(sq * 4 + j) ^ (srow & 15)][0] = pf[j];
        }
    }
#undef RD

    // butterfly over 64 lanes, then across the 4 waves
    #pragma unroll
    for (int p = 0; p < Pc; ++p) {
        float v = us[p];
        #pragma unroll
        for (int off = 32; off >= 1; off >>= 1)
            v += __shfl_xor(v, off, 64);
        us[p] = v;
    }
    if (lane == 0) {
        #pragma unroll
        for (int p = 0; p < Pc; ++p) wred[w][p] = us[p];
    }
    __syncthreads();
    if (tid < Pc) {
        float s = 0.f;
        #pragma unroll
        for (int k = 0; k < 4; ++k) s += wred[k][tid];
        partial[(size_t)bid * Pc + tid] = s;
    }
}

// reduce NBLKM block-partials x 8 poses -> 8 outputs
__global__ void ff_reduce(const float* __restrict__ partial, float* __restrict__ out)
{
    const int w    = threadIdx.x >> 6;
    const int lane = threadIdx.x & 63;
    float v = 0.f;
    #pragma unroll
    for (int j = 0; j < NBLKM / 64; ++j)
        v += partial[(size_t)(lane + 64 * j) * Pc + w];
    #pragma unroll
    for (int off = 32; off >= 1; off >>= 1)
        v += __shfl_xor(v, off, 64);
    if (lane == 0) out[w] = 0.1f * v;
}

extern "C" void kernel_launch(void* const* d_in, const int* in_sizes, int n_in,
                              void* d_out, int out_size, void* d_ws, size_t ws_size,
                              hipStream_t stream)
{
    const float* lig_feat   = (const float*)d_in[0];
    const float* rec_feat   = (const float*)d_in[1];
    const float* lig_coords = (const float*)d_in[2];
    const float* rec_coords = (const float*)d_in[3];
    float* out = (float*)d_out;

    float*          partial = (float*)d_ws;                                   // 32 KB
    unsigned short* ligE    = (unsigned short*)((char*)d_ws + 65536);         // 2 MB
    unsigned short* recE    = (unsigned short*)((char*)d_ws + 65536 + (2u << 20)); // 16 MB

    ff_cvt<<<(N4_LIG + N4_REC) / 256, 256, 0, stream>>>(lig_feat, rec_feat, ligE, recE);
    ff_mfma<<<NBLKM, 256, 0, stream>>>(ligE, recE, lig_coords, rec_coords, partial);
    ff_reduce<<<1, 512, 0, stream>>>(partial, out);
}

// Round 17
// 33.642 us; speedup vs baseline: 1.9557x; 1.3816x over previous
//
#include <hip/hip_runtime.h>
#include <math.h>

#define Lc 128
#define Rc 1024
#define Pc 8
#define Ec 64
#define Fc 64

// exp(-((d-mu)/sigma)^2) = exp2(-(C*(d-mu))^2), C = (1/0.15625)*sqrt(log2(e))
#define CSCALE   7.68718341623328f
#define MU_STEP  0.15873015873015873f   // 10/63
#define MUC      (MU_STEP * CSCALE)

#define BM 32        // l per block
#define BN 32        // r per block
#define EC 8         // e per block
#define NBLKM ((Lc/BM)*(Rc/BN)*(Ec/EC))   // 4*32*8 = 1024

typedef __attribute__((ext_vector_type(8))) short short8;   // 8 bf16
typedef __attribute__((ext_vector_type(4))) float f32x4;

__device__ __forceinline__ unsigned short bf16_rn(float x) {
    unsigned int u = __float_as_uint(x);
    u += 0x7FFF + ((u >> 16) & 1);
    return (unsigned short)(u >> 16);
}
// pack hi-bf16 (TRUNCATED) of two f32: one shr + one and-or
__device__ __forceinline__ unsigned int hipack(float x0, float x1) {
    return (__float_as_uint(x0) >> 16) | (__float_as_uint(x1) & 0xFFFF0000u);
}
// pack lo-bf16 (residual vs truncated hi) of two f32
__device__ __forceinline__ unsigned int lopack(float x0, float x1) {
    float r0 = x0 - __uint_as_float(__float_as_uint(x0) & 0xFFFF0000u);
    float r1 = x1 - __uint_as_float(__float_as_uint(x1) & 0xFFFF0000u);
    return ((unsigned int)bf16_rn(r1) << 16) | (unsigned int)bf16_rn(r0);
}

// ---- fused cvt+GEMM+fold: staging reads f32 sources directly, converts to
// split (hi,lo) bf16 in registers, writes XOR-swizzled LDS. No intermediate
// tensor, no cvt kernel. Compute structure identical to verified R16.
__global__ __launch_bounds__(256, 2)
void ff_mfma(const float* __restrict__ lig_feat,
             const float* __restrict__ rec_feat,
             const float* __restrict__ lig_coords,
             const float* __restrict__ rec_coords,
             float* __restrict__ partial)
{
    // [buf][A/B][row][slot 0..15][8 shorts]; slots 0-7 = hi(f=8s..8s+7), 8-15 = lo
    __shared__ __align__(16) unsigned short stg[2][2][32][16][8];   // 32 KB
    __shared__ float lcs[Pc][96];
    __shared__ float rcs[96];
    __shared__ float wred[4][Pc];

    const int tid  = threadIdx.x;
    const int lane = tid & 63;
    const int w    = tid >> 6;
    const int n16  = lane & 15;
    const int kg   = lane >> 4;
    const int sr   = w >> 1;            // subtile row (l)
    const int sc   = w & 1;             // subtile col (r)

    // grid decode; bid&7 = XCD: each XCD owns 4 r-tiles (rec slice L2-resident)
    const int bid = blockIdx.x;
    const int loc = bid >> 3;                   // 0..127
    const int rt  = (bid & 7) * 4 + (loc & 3);  // 0..31
    const int lt  = (loc >> 2) & 3;             // 0..3
    const int ez  = loc >> 4;                   // 0..7
    const int r0  = rt * BN;
    const int l0  = lt * BM;
    const int e0  = ez * EC;

    // coords -> LDS
    for (int i = tid; i < Pc * 96; i += 256) {
        int p = i / 96, q = i - p * 96;
        lcs[p][q] = lig_coords[p * (Lc * 3) + l0 * 3 + q];
    }
    if (tid < 96) rcs[tid] = rec_coords[r0 * 3 + tid];
    __syncthreads();

    // per-lane distances: l = sr*16 + kg*4 + reg, r = sc*16 + n16
    float dsc[Pc][4];
    {
        const int rb = (sc * 16 + n16) * 3;
        const float rx = rcs[rb], ry = rcs[rb + 1], rz = rcs[rb + 2];
        #pragma unroll
        for (int reg = 0; reg < 4; ++reg) {
            const int lb = (sr * 16 + kg * 4 + reg) * 3;
            #pragma unroll
            for (int p = 0; p < Pc; ++p) {
                float dx = lcs[p][lb]     - rx;
                float dy = lcs[p][lb + 1] - ry;
                float dz = lcs[p][lb + 2] - rz;
                dsc[p][reg] = sqrtf(dx * dx + dy * dy + dz * dz) * CSCALE;
            }
        }
    }

    // staging roles: half = A/B, srow = row, fq = f-quarter (16 f32 = 64 B/thread)
    const int half = tid >> 7;
    const int srow = (tid >> 2) & 31;
    const int fq   = tid & 3;
    const float* sbase = (half ? rec_feat + (size_t)(r0 + srow) * (Ec * Fc)
                               : lig_feat + (size_t)(l0 + srow) * (Ec * Fc)) + fq * 16;

    float4 pf[4];
    auto ld = [&](int e) {
        #pragma unroll
        for (int j = 0; j < 4; ++j)
            pf[j] = *(const float4*)(sbase + (size_t)e * Fc + j * 4);
    };
    auto cw = [&](int nb) {   // convert pf -> split bf16, write 4 swizzled slots
        uint4 H0, H1, L0, L1;
        H0.x = hipack(pf[0].x, pf[0].y); H0.y = hipack(pf[0].z, pf[0].w);
        H0.z = hipack(pf[1].x, pf[1].y); H0.w = hipack(pf[1].z, pf[1].w);
        H1.x = hipack(pf[2].x, pf[2].y); H1.y = hipack(pf[2].z, pf[2].w);
        H1.z = hipack(pf[3].x, pf[3].y); H1.w = hipack(pf[3].z, pf[3].w);
        L0.x = lopack(pf[0].x, pf[0].y); L0.y = lopack(pf[0].z, pf[0].w);
        L0.z = lopack(pf[1].x, pf[1].y); L0.w = lopack(pf[1].z, pf[1].w);
        L1.x = lopack(pf[2].x, pf[2].y); L1.y = lopack(pf[2].z, pf[2].w);
        L1.z = lopack(pf[3].x, pf[3].y); L1.w = lopack(pf[3].z, pf[3].w);
        const int sm = srow & 15;
        *(uint4*)&stg[nb][half][srow][(fq * 2)         ^ sm][0] = H0;
        *(uint4*)&stg[nb][half][srow][(fq * 2 + 1)     ^ sm][0] = H1;
        *(uint4*)&stg[nb][half][srow][(8 + fq * 2)     ^ sm][0] = L0;
        *(uint4*)&stg[nb][half][srow][(8 + fq * 2 + 1) ^ sm][0] = L1;
    };

    // prologue: stage e0 into buf 0; issue loads for e0+1
    ld(e0);
    cw(0);
    ld(e0 + 1);

    float us[Pc];
    #pragma unroll
    for (int p = 0; p < Pc; ++p) us[p] = 0.f;

    const int Arow = sr * 16 + n16;
    const int Brow = sc * 16 + n16;
#define RD(hf, rowv, slot) (*(const short8*)&stg[cur][hf][rowv][(slot) ^ ((rowv) & 15)][0])

    for (int t = 0; t < EC; ++t) {
        __syncthreads();                 // buf[t&1] visible; prev reads of buf[(t+1)&1] done
        const int cur = t & 1;

        // 6 split-MFMAs (hh + lh + hl; ll dropped, ~2^-16 rel)
        f32x4 acc = {0.f, 0.f, 0.f, 0.f};
        {
            short8 a0 = RD(0, Arow, kg);            // Ah0
            short8 b0 = RD(1, Brow, kg);            // Bh0
            acc = __builtin_amdgcn_mfma_f32_16x16x32_bf16(a0, b0, acc, 0, 0, 0);
            short8 a1 = RD(0, Arow, 8 + kg);        // Al0
            acc = __builtin_amdgcn_mfma_f32_16x16x32_bf16(a1, b0, acc, 0, 0, 0);
            short8 b1 = RD(1, Brow, 8 + kg);        // Bl0
            acc = __builtin_amdgcn_mfma_f32_16x16x32_bf16(a0, b1, acc, 0, 0, 0);
            a0 = RD(0, Arow, 4 + kg);               // Ah1
            b0 = RD(1, Brow, 4 + kg);               // Bh1
            acc = __builtin_amdgcn_mfma_f32_16x16x32_bf16(a0, b0, acc, 0, 0, 0);
            a1 = RD(0, Arow, 12 + kg);              // Al1
            acc = __builtin_amdgcn_mfma_f32_16x16x32_bf16(a1, b0, acc, 0, 0, 0);
            b1 = RD(1, Brow, 12 + kg);              // Bl1
            acc = __builtin_amdgcn_mfma_f32_16x16x32_bf16(a0, b1, acc, 0, 0, 0);
        }

        // fold atn into pose accumulators
        const float musC = (float)(e0 + t) * MUC;
        #pragma unroll
        for (int reg = 0; reg < 4; ++reg) {
            const float av = acc[reg];
            #pragma unroll
            for (int p = 0; p < Pc; ++p) {
                const float tt = dsc[p][reg] - musC;
                us[p] = fmaf(av, __builtin_amdgcn_exp2f(-tt * tt), us[p]);
            }
        }

        // convert + write next slice (loads issued a full step ago); then issue t+2
        if (t + 1 < EC) cw((t + 1) & 1);
        if (t + 2 < EC) ld(e0 + t + 2);
    }
#undef RD

    // butterfly over 64 lanes, then across the 4 waves
    #pragma unroll
    for (int p = 0; p < Pc; ++p) {
        float v = us[p];
        #pragma unroll
        for (int off = 32; off >= 1; off >>= 1)
            v += __shfl_xor(v, off, 64);
        us[p] = v;
    }
    if (lane == 0) {
        #pragma unroll
        for (int p = 0; p < Pc; ++p) wred[w][p] = us[p];
    }
    __syncthreads();
    if (tid < Pc) {
        float s = 0.f;
        #pragma unroll
        for (int k = 0; k < 4; ++k) s += wred[k][tid];
        partial[(size_t)bid * Pc + tid] = s;
    }
}

// reduce NBLKM block-partials x 8 poses -> 8 outputs
__global__ void ff_reduce(const float* __restrict__ partial, float* __restrict__ out)
{
    const int w    = threadIdx.x >> 6;
    const int lane = threadIdx.x & 63;
    float v = 0.f;
    #pragma unroll
    for (int j = 0; j < NBLKM / 64; ++j)
        v += partial[(size_t)(lane + 64 * j) * Pc + w];
    #pragma unroll
    for (int off = 32; off >= 1; off >>= 1)
        v += __shfl_xor(v, off, 64);
    if (lane == 0) out[w] = 0.1f * v;
}

extern "C" void kernel_launch(void* const* d_in, const int* in_sizes, int n_in,
                              void* d_out, int out_size, void* d_ws, size_t ws_size,
                              hipStream_t stream)
{
    const float* lig_feat   = (const float*)d_in[0];
    const float* rec_feat   = (const float*)d_in[1];
    const float* lig_coords = (const float*)d_in[2];
    const float* rec_coords = (const float*)d_in[3];
    float* out     = (float*)d_out;
    float* partial = (float*)d_ws;   // 1024*8*4 = 32 KB

    ff_mfma<<<NBLKM, 256, 0, stream>>>(lig_feat, rec_feat, lig_coords, rec_coords, partial);
    ff_reduce<<<1, 512, 0, stream>>>(partial, out);
}